// Round 6
// baseline (190.420 us; speedup 1.0000x reference)
//
#include <hip/hip_runtime.h>
#include <hip/hip_fp16.h>
#include <math.h>

#define N_NODES 10000
#define N_EDGES 640000
#define DIM     128
#define NCLS    10
#define NGRAPH  64
#define NB      157    // buckets of 64 nodes (dst>>6)
#define NBB     160    // bin blocks
#define SEG     64     // slots per (bucket, bin-block); cnt~Poisson(25.5), +7.6 sigma
#define EPB     4000   // edges per bin-block
#define NPB     8      // nodes per fused-layer block (1250 blocks)

typedef unsigned int uint32;
typedef unsigned short ushort16;
typedef _Float16 h2v __attribute__((ext_vector_type(2)));

#define SEL_LO 0x00003C00u   // f16x2 (1.0, 0.0)
#define SEL_HI 0x3C000000u   // f16x2 (0.0, 1.0)

__device__ __forceinline__ h2v as_h2(uint32 u) { h2v r; __builtin_memcpy(&r, &u, 4); return r; }

// acc += w.lo*p.lo + w.hi*p.hi  (packed f16 dot2, f32 accumulate)
__device__ __forceinline__ float fd2(uint32 w, uint32 p, float acc) {
#if __has_builtin(__builtin_amdgcn_fdot2)
    return __builtin_amdgcn_fdot2(as_h2(w), as_h2(p), acc, false);
#else
    h2v a = as_h2(w), b = as_h2(p);
    return acc + (float)a[0] * (float)b[0] + (float)a[1] * (float)b[1];
#endif
}
__device__ __forceinline__ float f16lo(uint32 u) { return (float)as_h2(u)[0]; }
__device__ __forceinline__ float f16hi(uint32 u) { return (float)as_h2(u)[1]; }
__device__ __forceinline__ ushort16 f32_f16(float f) {
    return __half_as_ushort(__float2half(f));
}
__device__ __forceinline__ uint32 pack_f16x2(float lo, float hi) {
    __half2 h = __floats2half2_rn(lo, hi);
    uint32 u; __builtin_memcpy(&u, &h, 4); return u;
}

// ---------------- pass A: bin (atomic-free, private segments) + layer-1 GEMM
//                  + xr zero + W2-4 f16 prepack ----------------
// Blocks 0..624: g1 = f16(x @ W1) (unscaled; binB folds the dis scale in).
// Blocks 625..784: bin 4000 edges into private per-(bucket,block) segments.
// Block 785: zero out_xr. Blocks 786..788: prepack W2/W3/W4 to f16 pairs.
// No global atomics anywhere; no pre-zeroed workspace needed (kills the
// gcursor memset dispatch).
__global__ __launch_bounds__(256) void binA_gemm1(const int* __restrict__ src,
                                                  const int* __restrict__ dst,
                                                  int* __restrict__ cntG,
                                                  uint32* __restrict__ bins,
                                                  const float* __restrict__ X,
                                                  const float* __restrict__ W,
                                                  const float* __restrict__ W2,
                                                  const float* __restrict__ W3,
                                                  const float* __restrict__ W4,
                                                  uint32* __restrict__ Wp,
                                                  ushort16* __restrict__ Gh,
                                                  float* __restrict__ xr) {
    __shared__ uint32 pk[EPB];
    __shared__ int cntS[NB], offS[NB], curS[NB];

    if (blockIdx.x < 625) {
        int c    = threadIdx.x & 127;
        int rg   = threadIdx.x >> 7;
        int row0 = blockIdx.x * 16 + rg * 8;
        const float* xb = X + row0 * DIM;
        float acc[8] = {0.f, 0.f, 0.f, 0.f, 0.f, 0.f, 0.f, 0.f};
        for (int k = 0; k < DIM; k += 4) {
            float w0 = W[(k + 0) * DIM + c];
            float w1 = W[(k + 1) * DIM + c];
            float w2 = W[(k + 2) * DIM + c];
            float w3 = W[(k + 3) * DIM + c];
#pragma unroll
            for (int r = 0; r < 8; r++) {
                float4 xv = *(const float4*)(xb + r * DIM + k);
                acc[r] += xv.x * w0 + xv.y * w1 + xv.z * w2 + xv.w * w3;
            }
        }
#pragma unroll
        for (int r = 0; r < 8; r++)
            Gh[(row0 + r) * DIM + c] = f32_f16(acc[r]);
        return;
    }

    if (blockIdx.x >= 786) {
        int w = blockIdx.x - 786;                    // 0..2 -> W2,W3,W4
        const float* Ws = (w == 0) ? W2 : (w == 1) ? W3 : W4;
        uint32* Wd = Wp + w * (64 * DIM);
        for (int i = threadIdx.x; i < 64 * DIM; i += 256) {
            int k2 = i >> 7, c = i & 127;
            Wd[i] = pack_f16x2(Ws[(2 * k2) * DIM + c], Ws[(2 * k2 + 1) * DIM + c]);
        }
        return;
    }

    if (blockIdx.x == 785) {
        float4 z = make_float4(0.f, 0.f, 0.f, 0.f);
        for (int j = threadIdx.x; j < NGRAPH * DIM / 4; j += 256)
            ((float4*)xr)[j] = z;
        return;
    }

    int ab  = blockIdx.x - 625;     // 0..159
    int tid = threadIdx.x;
    for (int i = tid; i < NB; i += 256) cntS[i] = 0;
    __syncthreads();

    int base = ab * EPB;
    uint32 pr[16];
#pragma unroll
    for (int it = 0; it < 16; it++) {
        int i = it * 256 + tid;
        uint32 p = 0xffffffffu;
        if (i < EPB) {
            int e = base + i;
            p = ((uint32)dst[e] << 16) | (uint32)src[e];
            atomicAdd(&cntS[p >> 22], 1);     // p>>22 == dst>>6 ; LDS atomic
        }
        pr[it] = p;
    }
    __syncthreads();

    // exclusive scan of cntS by wave 0 (3 rounds of 64)
    if (tid < 64) {
        int carry = 0;
        for (int r = 0; r < 3; r++) {
            int idx = r * 64 + tid;
            int v = (idx < NB) ? cntS[idx] : 0;
            int inc = v;
#pragma unroll
            for (int o = 1; o < 64; o <<= 1) {
                int u = __shfl_up(inc, o, 64);
                if (tid >= o) inc += u;
            }
            if (idx < NB) { offS[idx] = inc - v + carry; curS[idx] = inc - v + carry; }
            carry += __shfl(inc, 63, 64);
        }
    }
    __syncthreads();

    // relocate into LDS so segment writes are sequential runs per bucket
#pragma unroll
    for (int it = 0; it < 16; it++) {
        uint32 p = pr[it];
        if (p != 0xffffffffu) {
            int b = p >> 22;
            pk[atomicAdd(&curS[b], 1)] = p;
        }
    }
    __syncthreads();

    // write runs into this block's private segments; plain count stores
#pragma unroll
    for (int it = 0; it < 16; it++) {
        int i = it * 256 + tid;
        if (i < EPB) {
            uint32 u = pk[i];
            int b = u >> 22;
            int gp = i - offS[b];
            if (gp < SEG) bins[(size_t)(b * NBB + ab) * SEG + gp] = u;
        }
    }
    if (tid < NB) {
        int c = cntS[tid];
        cntG[tid * NBB + ab] = c < SEG ? c : SEG;
    }
}

// ---------------- pass B: segments -> padded adjacency (2 blocks/bucket)
//                  + fold dis scale into Gh (h1) ----------------
__global__ __launch_bounds__(256) void binB2(const int* __restrict__ cntG,
                                             const uint32* __restrict__ bins,
                                             ushort16* __restrict__ col,
                                             int* __restrict__ deg,
                                             float* __restrict__ dis,
                                             ushort16* __restrict__ Gh) {
    __shared__ ushort16 adj[32 * 128];   // 8 KB
    __shared__ int cnt2[32];
    __shared__ int segc[NBB];
    int b    = blockIdx.x >> 1;
    int half = blockIdx.x & 1;
    int tid  = threadIdx.x;
    if (tid < 32) cnt2[tid] = 0;
    if (tid < NBB) segc[tid] = cntG[b * NBB + tid];
    __syncthreads();

    const uint32* bb = bins + (size_t)b * NBB * SEG;
    for (int i = tid; i < NBB * SEG; i += 256) {       // coalesced linear scan
        int seg = i >> 6, idx = i & 63;
        if (idx < segc[seg]) {
            uint32 u = bb[i];
            int local = (u >> 16) & 63;
            if ((local >> 5) == half) {
                int l5 = local & 31;
                int r = atomicAdd(&cnt2[l5], 1);
                if (r < 128) adj[(l5 << 7) + r] = (ushort16)(u & 0xffffu);
            }
        }
    }
    __syncthreads();

    uint4* dstp = (uint4*)(col + (size_t)b * 64 * 128 + half * 32 * 128);
    const uint4* srcp = (const uint4*)adj;
    for (int j = tid; j < 512; j += 256) dstp[j] = srcp[j];
    if (tid < 32) {
        int node = b * 64 + half * 32 + tid;   // arrays padded to 10240
        int c = cnt2[tid] < 128 ? cnt2[tid] : 128;
        deg[node] = c;
        dis[node] = rsqrtf((float)c + 1.0f);
    }

    // epilogue: scale this block's 32 Gh rows (h1) by dis in-place so the
    // layer-2 agg needs no per-edge dis gathers (same path as layers 3/4).
    uint4* Gh4 = (uint4*)Gh;
    int node0 = b * 64 + half * 32;
    for (int j = tid; j < 32 * 16; j += 256) {
        int rl = j >> 4, q = j & 15;
        if (node0 + rl >= N_NODES) continue;
        int c = cnt2[rl] < 128 ? cnt2[rl] : 128;
        float dv = rsqrtf((float)c + 1.0f);
        uint4 g = Gh4[(size_t)(node0 + rl) * 16 + q];
        g.x = pack_f16x2(f16lo(g.x) * dv, f16hi(g.x) * dv);
        g.y = pack_f16x2(f16lo(g.y) * dv, f16hi(g.y) * dv);
        g.z = pack_f16x2(f16lo(g.z) * dv, f16hi(g.z) * dv);
        g.w = pack_f16x2(f16lo(g.w) * dv, f16hi(g.w) * dv);
        Gh4[(size_t)(node0 + rl) * 16 + q] = g;
    }
}

// ---------------- fused agg via packed-f16 dot2 -> LDS (input always prescaled) ----
template <bool PACK_OUT>
__device__ __forceinline__ void agg_to_lds(const ushort16* __restrict__ Gh,
                                           const int* __restrict__ deg,
                                           const ushort16* __restrict__ col,
                                           const float* __restrict__ dis,
                                           void* __restrict__ Xout) {
    int tid  = threadIdx.x;
    int wave = tid >> 6;
    int lane = tid & 63;
    int grp  = lane >> 4;       // 0..3 : which edge of the 4-per-load
    int sl   = lane & 15;       // 0..15: 16B slice of the 256B row
    const uint32* g32 = (const uint32*)Gh;
    const uint32* gp  = g32 + (sl << 2);   // +sl*16B within a row

#pragma unroll
    for (int i = 0; i < 2; i++) {
        int vr = wave * 2 + i;              // local node 0..7
        int v  = blockIdx.x * NPB + vr;
        int dv = deg[v];
        uint32 colpack = ((const uint32*)(col + ((size_t)v << 7)))[lane];
        float acc[8];
#pragma unroll
        for (int j = 0; j < 8; j++) acc[j] = 0.f;

        int kk = 0;
        for (; kk + 16 <= dv; kk += 16) {
            int k0 = kk + grp, k1 = kk + 4 + grp, k2 = kk + 8 + grp, k3 = kk + 12 + grp;
            uint32 cp0 = __shfl(colpack, k0 >> 1, 64);
            uint32 cp1 = __shfl(colpack, k1 >> 1, 64);
            uint32 cp2 = __shfl(colpack, k2 >> 1, 64);
            uint32 cp3 = __shfl(colpack, k3 >> 1, 64);
            int u0 = (k0 & 1) ? (int)(cp0 >> 16) : (int)(cp0 & 0xffffu);
            int u1 = (k1 & 1) ? (int)(cp1 >> 16) : (int)(cp1 & 0xffffu);
            int u2 = (k2 & 1) ? (int)(cp2 >> 16) : (int)(cp2 & 0xffffu);
            int u3 = (k3 & 1) ? (int)(cp3 >> 16) : (int)(cp3 & 0xffffu);
            uint4 w0 = *(const uint4*)(gp + (u0 << 6));
            uint4 w1 = *(const uint4*)(gp + (u1 << 6));
            uint4 w2 = *(const uint4*)(gp + (u2 << 6));
            uint4 w3 = *(const uint4*)(gp + (u3 << 6));
            acc[0] = fd2(w0.x, SEL_LO, acc[0]); acc[1] = fd2(w0.x, SEL_HI, acc[1]);
            acc[2] = fd2(w0.y, SEL_LO, acc[2]); acc[3] = fd2(w0.y, SEL_HI, acc[3]);
            acc[4] = fd2(w0.z, SEL_LO, acc[4]); acc[5] = fd2(w0.z, SEL_HI, acc[5]);
            acc[6] = fd2(w0.w, SEL_LO, acc[6]); acc[7] = fd2(w0.w, SEL_HI, acc[7]);
            acc[0] = fd2(w1.x, SEL_LO, acc[0]); acc[1] = fd2(w1.x, SEL_HI, acc[1]);
            acc[2] = fd2(w1.y, SEL_LO, acc[2]); acc[3] = fd2(w1.y, SEL_HI, acc[3]);
            acc[4] = fd2(w1.z, SEL_LO, acc[4]); acc[5] = fd2(w1.z, SEL_HI, acc[5]);
            acc[6] = fd2(w1.w, SEL_LO, acc[6]); acc[7] = fd2(w1.w, SEL_HI, acc[7]);
            acc[0] = fd2(w2.x, SEL_LO, acc[0]); acc[1] = fd2(w2.x, SEL_HI, acc[1]);
            acc[2] = fd2(w2.y, SEL_LO, acc[2]); acc[3] = fd2(w2.y, SEL_HI, acc[3]);
            acc[4] = fd2(w2.z, SEL_LO, acc[4]); acc[5] = fd2(w2.z, SEL_HI, acc[5]);
            acc[6] = fd2(w2.w, SEL_LO, acc[6]); acc[7] = fd2(w2.w, SEL_HI, acc[7]);
            acc[0] = fd2(w3.x, SEL_LO, acc[0]); acc[1] = fd2(w3.x, SEL_HI, acc[1]);
            acc[2] = fd2(w3.y, SEL_LO, acc[2]); acc[3] = fd2(w3.y, SEL_HI, acc[3]);
            acc[4] = fd2(w3.z, SEL_LO, acc[4]); acc[5] = fd2(w3.z, SEL_HI, acc[5]);
            acc[6] = fd2(w3.w, SEL_LO, acc[6]); acc[7] = fd2(w3.w, SEL_HI, acc[7]);
        }
        for (; kk + 8 <= dv; kk += 8) {
            int k0 = kk + grp, k1 = kk + 4 + grp;
            uint32 cp0 = __shfl(colpack, k0 >> 1, 64);
            uint32 cp1 = __shfl(colpack, k1 >> 1, 64);
            int u0 = (k0 & 1) ? (int)(cp0 >> 16) : (int)(cp0 & 0xffffu);
            int u1 = (k1 & 1) ? (int)(cp1 >> 16) : (int)(cp1 & 0xffffu);
            uint4 w0 = *(const uint4*)(gp + (u0 << 6));
            uint4 w1 = *(const uint4*)(gp + (u1 << 6));
            acc[0] = fd2(w0.x, SEL_LO, acc[0]); acc[1] = fd2(w0.x, SEL_HI, acc[1]);
            acc[2] = fd2(w0.y, SEL_LO, acc[2]); acc[3] = fd2(w0.y, SEL_HI, acc[3]);
            acc[4] = fd2(w0.z, SEL_LO, acc[4]); acc[5] = fd2(w0.z, SEL_HI, acc[5]);
            acc[6] = fd2(w0.w, SEL_LO, acc[6]); acc[7] = fd2(w0.w, SEL_HI, acc[7]);
            acc[0] = fd2(w1.x, SEL_LO, acc[0]); acc[1] = fd2(w1.x, SEL_HI, acc[1]);
            acc[2] = fd2(w1.y, SEL_LO, acc[2]); acc[3] = fd2(w1.y, SEL_HI, acc[3]);
            acc[4] = fd2(w1.z, SEL_LO, acc[4]); acc[5] = fd2(w1.z, SEL_HI, acc[5]);
            acc[6] = fd2(w1.w, SEL_LO, acc[6]); acc[7] = fd2(w1.w, SEL_HI, acc[7]);
        }
        for (; kk < dv; kk += 4) {
            int k = kk + grp;
            uint32 cp = __shfl(colpack, (k >> 1) & 63, 64);
            int u = (k & 1) ? (int)(cp >> 16) : (int)(cp & 0xffffu);
            if (k < dv) {
                uint4 w = *(const uint4*)(gp + (u << 6));
                acc[0] = fd2(w.x, SEL_LO, acc[0]); acc[1] = fd2(w.x, SEL_HI, acc[1]);
                acc[2] = fd2(w.y, SEL_LO, acc[2]); acc[3] = fd2(w.y, SEL_HI, acc[3]);
                acc[4] = fd2(w.z, SEL_LO, acc[4]); acc[5] = fd2(w.z, SEL_HI, acc[5]);
                acc[6] = fd2(w.w, SEL_LO, acc[6]); acc[7] = fd2(w.w, SEL_HI, acc[7]);
            }
        }
#pragma unroll
        for (int j = 0; j < 8; j++) {
            acc[j] += __shfl_xor(acc[j], 16, 64);
            acc[j] += __shfl_xor(acc[j], 32, 64);
        }
        float sv = dis[v];
        uint4 hs = *(const uint4*)(gp + (v << 6));
        float r0 = sv * (acc[0] + f16lo(hs.x));
        float r1 = sv * (acc[1] + f16hi(hs.x));
        float r2 = sv * (acc[2] + f16lo(hs.y));
        float r3 = sv * (acc[3] + f16hi(hs.y));
        float r4 = sv * (acc[4] + f16lo(hs.z));
        float r5 = sv * (acc[5] + f16hi(hs.z));
        float r6 = sv * (acc[6] + f16lo(hs.w));
        float r7 = sv * (acc[7] + f16hi(hs.w));
        if (grp == 0) {
            if (PACK_OUT) {
                uint32* o = (uint32*)Xout + vr * 64 + sl * 4;
                uint4 pk4;
                pk4.x = pack_f16x2(fmaxf(r0, 0.f), fmaxf(r1, 0.f));
                pk4.y = pack_f16x2(fmaxf(r2, 0.f), fmaxf(r3, 0.f));
                pk4.z = pack_f16x2(fmaxf(r4, 0.f), fmaxf(r5, 0.f));
                pk4.w = pack_f16x2(fmaxf(r6, 0.f), fmaxf(r7, 0.f));
                *(uint4*)o = pk4;
            } else {
                float4* o = (float4*)((float*)Xout + vr * DIM + sl * 8);
                o[0] = make_float4(fmaxf(r0, 0.f), fmaxf(r1, 0.f),
                                   fmaxf(r2, 0.f), fmaxf(r3, 0.f));
                o[1] = make_float4(fmaxf(r4, 0.f), fmaxf(r5, 0.f),
                                   fmaxf(r6, 0.f), fmaxf(r7, 0.f));
            }
        }
    }
}

// ---------------- fused layer: dot2-agg (packed LDS) + dot2-GEMM ----------------
__global__ __launch_bounds__(256) void fused_layer(const ushort16* __restrict__ Gh_in,
                                                   const int* __restrict__ deg,
                                                   const ushort16* __restrict__ col,
                                                   const float* __restrict__ dis,
                                                   const uint32* __restrict__ Wp,
                                                   ushort16* __restrict__ Gh_out) {
    __shared__ __align__(16) uint32 Xh[NPB * 64];   // 2 KB packed f16 pairs
    agg_to_lds<true>(Gh_in, deg, col, dis, Xh);
    __syncthreads();

    int c  = threadIdx.x & 127;
    int rg = threadIdx.x >> 7;
    int row0 = blockIdx.x * NPB + rg * 4;
    const uint4* Xh4 = (const uint4*)Xh;
    float acc[4] = {0.f, 0.f, 0.f, 0.f};
    for (int q = 0; q < 16; q++) {
        uint32 wp0 = Wp[(4 * q + 0) * DIM + c];
        uint32 wp1 = Wp[(4 * q + 1) * DIM + c];
        uint32 wp2 = Wp[(4 * q + 2) * DIM + c];
        uint32 wp3 = Wp[(4 * q + 3) * DIM + c];
#pragma unroll
        for (int r = 0; r < 4; r++) {
            uint4 xv = Xh4[(rg * 4 + r) * 16 + q];
            acc[r] = fd2(xv.x, wp0, acc[r]);
            acc[r] = fd2(xv.y, wp1, acc[r]);
            acc[r] = fd2(xv.z, wp2, acc[r]);
            acc[r] = fd2(xv.w, wp3, acc[r]);
        }
    }
#pragma unroll
    for (int r = 0; r < 4; r++) {
        int row = row0 + r;
        Gh_out[row * DIM + c] = f32_f16(acc[r] * dis[row]);
    }
}

// ---------------- fused last: dot2-agg (f32 LDS) + head + pool ----------------
__global__ __launch_bounds__(256) void fused_last(const ushort16* __restrict__ Gh_in,
                                                  const int* __restrict__ deg,
                                                  const ushort16* __restrict__ col,
                                                  const float* __restrict__ dis,
                                                  const int* __restrict__ batch,
                                                  const float* __restrict__ fcw,
                                                  const float* __restrict__ fcb,
                                                  float* __restrict__ xr,
                                                  float* __restrict__ out) {
    __shared__ float Xs[NPB * DIM];
    agg_to_lds<false>(Gh_in, deg, col, dis, Xs);
    __syncthreads();

    int wave = threadIdx.x >> 6;
    int lane = threadIdx.x & 63;
#pragma unroll
    for (int i = 0; i < 2; i++) {
        int vr   = wave * 2 + i;
        int node = blockIdx.x * NPB + vr;
        float xl = Xs[vr * DIM + lane];
        float xh = Xs[vr * DIM + 64 + lane];
        float lg[NCLS];
#pragma unroll
        for (int c2 = 0; c2 < NCLS; c2++) {
            float p = xl * fcw[lane * NCLS + c2] + xh * fcw[(lane + 64) * NCLS + c2];
#pragma unroll
            for (int off = 32; off >= 1; off >>= 1) p += __shfl_xor(p, off, 64);
            lg[c2] = p + fcb[c2];
        }
        float m = lg[0];
#pragma unroll
        for (int c2 = 1; c2 < NCLS; c2++) m = fmaxf(m, lg[c2]);
        float s = 0.f;
#pragma unroll
        for (int c2 = 0; c2 < NCLS; c2++) s += expf(lg[c2] - m);
        float lse = m + logf(s);
        if (lane < NCLS) out[node * NCLS + lane] = lg[lane] - lse;
    }

    // pool: batch is sorted, run-length flush (<= ~1 extra flush per block)
    if (threadIdx.x < 128) {
        int start = blockIdx.x * NPB;
        int t = threadIdx.x;
        int b = batch[start];
        float a = 0.f;
        for (int n = 0; n < NPB; n++) {
            int bn = batch[start + n];
            if (bn != b) { atomicAdd(&xr[b * DIM + t], a); a = 0.f; b = bn; }
            a += Xs[n * DIM + t];
        }
        atomicAdd(&xr[b * DIM + t], a);
    }
}

// ---------------- launch ----------------

extern "C" void kernel_launch(void* const* d_in, const int* in_sizes, int n_in,
                              void* d_out, int out_size, void* d_ws, size_t ws_size,
                              hipStream_t stream) {
    const float* x     = (const float*)d_in[0];
    const int*   ei    = (const int*)d_in[1];      // [2, E] int32
    const int*   src   = ei;
    const int*   dst   = ei + N_EDGES;
    const int*   batch = (const int*)d_in[2];
    const float* W1    = (const float*)d_in[3];
    const float* W2    = (const float*)d_in[4];
    const float* W3    = (const float*)d_in[5];
    const float* W4    = (const float*)d_in[6];
    const float* fcw   = (const float*)d_in[7];
    const float* fcb   = (const float*)d_in[8];

    float* out_ls = (float*)d_out;                 // [N,10]
    float* out_xr = out_ls + N_NODES * NCLS;       // [64,128]

    // workspace layout (16B-aligned element offsets); nothing needs pre-zeroing
    int*      cntG = (int*)d_ws;                          // NB*NBB ints (100KB)
    int*      deg  = cntG + NB * NBB;                     // 10240 ints
    float*    dis  = (float*)(deg + 10240);               // 10240 floats
    uint32*   bins = (uint32*)(dis + 10240);              // NB*NBB*SEG uint32 (6.43MB)
    ushort16* col  = (ushort16*)(bins + (size_t)NB * NBB * SEG); // NB*64*128 ushorts
    ushort16* Gh_a = col + (size_t)NB * 64 * 128;         // N*D f16
    ushort16* Gh_b = Gh_a + (size_t)N_NODES * DIM;        // N*D f16
    uint32*   Wp   = (uint32*)(Gh_b + (size_t)N_NODES * DIM); // 3*64*128 f16-pairs

    binA_gemm1<<<789, 256, 0, stream>>>(src, dst, cntG, bins, x, W1,
                                        W2, W3, W4, Wp, Gh_a, out_xr);
    binB2     <<<2 * NB, 256, 0, stream>>>(cntG, bins, col, deg, dis, Gh_a);

    fused_layer<<<N_NODES / NPB, 256, 0, stream>>>(Gh_a, deg, col, dis, Wp, Gh_b);
    fused_layer<<<N_NODES / NPB, 256, 0, stream>>>(Gh_b, deg, col, dis,
                                                   Wp + 64 * DIM, Gh_a);
    fused_layer<<<N_NODES / NPB, 256, 0, stream>>>(Gh_a, deg, col, dis,
                                                   Wp + 2 * 64 * DIM, Gh_b);
    fused_last <<<N_NODES / NPB, 256, 0, stream>>>(Gh_b, deg, col, dis, batch,
                                                   fcw, fcb, out_xr, out_ls);
}

// Round 7
// 180.959 us; speedup vs baseline: 1.0523x; 1.0523x over previous
//
#include <hip/hip_runtime.h>
#include <hip/hip_fp16.h>
#include <math.h>

#define N_NODES 10000
#define N_EDGES 640000
#define DIM     128
#define NCLS    10
#define NGRAPH  64
#define NB      157    // buckets of 64 nodes (dst>>6)
#define BCAP    4608   // bucket capacity; bucket ~Poisson(4076), 8 sigma pad
#define EPB     4000   // edges per bin-block (160 blocks)
#define NPB     8      // nodes per fused-layer block (1250 blocks)

typedef unsigned int uint32;
typedef unsigned short ushort16;
typedef _Float16 h2v __attribute__((ext_vector_type(2)));

#define SEL_LO 0x00003C00u   // f16x2 (1.0, 0.0)
#define SEL_HI 0x3C000000u   // f16x2 (0.0, 1.0)

__device__ __forceinline__ h2v as_h2(uint32 u) { h2v r; __builtin_memcpy(&r, &u, 4); return r; }

// acc += w.lo*p.lo + w.hi*p.hi  (packed f16 dot2, f32 accumulate)
__device__ __forceinline__ float fd2(uint32 w, uint32 p, float acc) {
#if __has_builtin(__builtin_amdgcn_fdot2)
    return __builtin_amdgcn_fdot2(as_h2(w), as_h2(p), acc, false);
#else
    h2v a = as_h2(w), b = as_h2(p);
    return acc + (float)a[0] * (float)b[0] + (float)a[1] * (float)b[1];
#endif
}
__device__ __forceinline__ float f16lo(uint32 u) { return (float)as_h2(u)[0]; }
__device__ __forceinline__ float f16hi(uint32 u) { return (float)as_h2(u)[1]; }
__device__ __forceinline__ ushort16 f32_f16(float f) {
    return __half_as_ushort(__float2half(f));
}
__device__ __forceinline__ uint32 pack_f16x2(float lo, float hi) {
    __half2 h = __floats2half2_rn(lo, hi);
    uint32 u; __builtin_memcpy(&u, &h, 4); return u;
}

// ---------------- pass A: bin + layer-1 GEMM + xr zero + W2-4 f16 prepack ----------
// Blocks 0..624: g1 = f16(x @ W1) (unscaled; binB folds the dis scale in).
// Blocks 625..784: bin 4000 edges each (R5's contiguous-run atomic scheme —
// R6's private segments regressed: padded scans + scattered short runs).
// Block 785: zero out_xr. Blocks 786..788: prepack W2/W3/W4 to f16 pairs.
__global__ __launch_bounds__(256) void binA_gemm1(const int* __restrict__ src,
                                                  const int* __restrict__ dst,
                                                  int* __restrict__ gcursor,
                                                  uint32* __restrict__ bins,
                                                  const float* __restrict__ X,
                                                  const float* __restrict__ W,
                                                  const float* __restrict__ W2,
                                                  const float* __restrict__ W3,
                                                  const float* __restrict__ W4,
                                                  uint32* __restrict__ Wp,
                                                  ushort16* __restrict__ Gh,
                                                  float* __restrict__ xr) {
    __shared__ uint32 pk[EPB];
    __shared__ int cntS[NB], offS[NB], curS[NB], gposS[NB];

    if (blockIdx.x < 625) {
        int c    = threadIdx.x & 127;
        int rg   = threadIdx.x >> 7;
        int row0 = blockIdx.x * 16 + rg * 8;
        const float* xb = X + row0 * DIM;
        float acc[8] = {0.f, 0.f, 0.f, 0.f, 0.f, 0.f, 0.f, 0.f};
        for (int k = 0; k < DIM; k += 4) {
            float w0 = W[(k + 0) * DIM + c];
            float w1 = W[(k + 1) * DIM + c];
            float w2 = W[(k + 2) * DIM + c];
            float w3 = W[(k + 3) * DIM + c];
#pragma unroll
            for (int r = 0; r < 8; r++) {
                float4 xv = *(const float4*)(xb + r * DIM + k);
                acc[r] += xv.x * w0 + xv.y * w1 + xv.z * w2 + xv.w * w3;
            }
        }
#pragma unroll
        for (int r = 0; r < 8; r++)
            Gh[(row0 + r) * DIM + c] = f32_f16(acc[r]);
        return;
    }

    if (blockIdx.x >= 786) {
        int w = blockIdx.x - 786;                    // 0..2 -> W2,W3,W4
        const float* Ws = (w == 0) ? W2 : (w == 1) ? W3 : W4;
        uint32* Wd = Wp + w * (64 * DIM);
        for (int i = threadIdx.x; i < 64 * DIM; i += 256) {
            int k2 = i >> 7, c = i & 127;
            Wd[i] = pack_f16x2(Ws[(2 * k2) * DIM + c], Ws[(2 * k2 + 1) * DIM + c]);
        }
        return;
    }

    if (blockIdx.x == 785) {
        float4 z = make_float4(0.f, 0.f, 0.f, 0.f);
        for (int j = threadIdx.x; j < NGRAPH * DIM / 4; j += 256)
            ((float4*)xr)[j] = z;
        return;
    }

    int ab  = blockIdx.x - 625;     // 0..159
    int tid = threadIdx.x;
    for (int i = tid; i < NB; i += 256) cntS[i] = 0;
    __syncthreads();

    int base = ab * EPB;
    uint32 pr[16];
#pragma unroll
    for (int it = 0; it < 16; it++) {
        int i = it * 256 + tid;
        uint32 p = 0xffffffffu;
        if (i < EPB) {
            int e = base + i;
            p = ((uint32)dst[e] << 16) | (uint32)src[e];
            atomicAdd(&cntS[p >> 22], 1);     // p>>22 == dst>>6 ; LDS atomic
        }
        pr[it] = p;
    }
    __syncthreads();

    // exclusive scan of cntS by wave 0 (3 rounds of 64)
    if (tid < 64) {
        int carry = 0;
        for (int r = 0; r < 3; r++) {
            int idx = r * 64 + tid;
            int v = (idx < NB) ? cntS[idx] : 0;
            int inc = v;
#pragma unroll
            for (int o = 1; o < 64; o <<= 1) {
                int u = __shfl_up(inc, o, 64);
                if (tid >= o) inc += u;
            }
            if (idx < NB) { offS[idx] = inc - v + carry; curS[idx] = inc - v + carry; }
            carry += __shfl(inc, 63, 64);
        }
    }
    __syncthreads();

    // relocate into LDS so global writes are sequential runs
#pragma unroll
    for (int it = 0; it < 16; it++) {
        uint32 p = pr[it];
        if (p != 0xffffffffu) {
            int b = p >> 22;
            pk[atomicAdd(&curS[b], 1)] = p;
        }
    }
    __syncthreads();

    if (tid < NB) gposS[tid] = atomicAdd(&gcursor[tid], cntS[tid]);
    __syncthreads();

#pragma unroll
    for (int it = 0; it < 16; it++) {
        int i = it * 256 + tid;
        if (i < EPB) {
            uint32 u = pk[i];
            int b = u >> 22;
            int gp = gposS[b] + (i - offS[b]);
            if (gp < BCAP) bins[b * BCAP + gp] = u;
        }
    }
}

// ---------------- pass B: bucket -> padded adjacency (2 blocks/bucket)
//                  + fold dis scale into Gh (h1) in-place ----------------
__global__ __launch_bounds__(256) void binB2(const int* __restrict__ gcursor,
                                             const uint32* __restrict__ bins,
                                             ushort16* __restrict__ col,
                                             int* __restrict__ deg,
                                             float* __restrict__ dis,
                                             ushort16* __restrict__ Gh) {
    __shared__ ushort16 adj[32 * 128];   // 8 KB
    __shared__ int cnt2[32];
    int b    = blockIdx.x >> 1;
    int half = blockIdx.x & 1;
    int tid  = threadIdx.x;
    if (tid < 32) cnt2[tid] = 0;
    __syncthreads();
    int tc = gcursor[b];
    if (tc > BCAP) tc = BCAP;
    const uint32* bb = bins + b * BCAP;
    for (int i = tid; i < tc; i += 256) {
        uint32 u = bb[i];
        int local = (u >> 16) & 63;
        if ((local >> 5) == half) {
            int l5 = local & 31;
            int r = atomicAdd(&cnt2[l5], 1);
            if (r < 128) adj[(l5 << 7) + r] = (ushort16)(u & 0xffffu);
        }
    }
    __syncthreads();
    uint4* dstp = (uint4*)(col + (size_t)b * 64 * 128 + half * 32 * 128);
    const uint4* srcp = (const uint4*)adj;
    for (int j = tid; j < 512; j += 256) dstp[j] = srcp[j];
    if (tid < 32) {
        int node = b * 64 + half * 32 + tid;   // arrays padded to 10240
        int c = cnt2[tid] < 128 ? cnt2[tid] : 128;
        deg[node] = c;
        dis[node] = rsqrtf((float)c + 1.0f);
    }

    // epilogue: scale this block's 32 Gh (h1) rows by dis in place -> the
    // layer-1 agg needs no per-edge dis gathers (same SEL path as layers 2/3).
    uint4* Gh4 = (uint4*)Gh;
    int node0 = b * 64 + half * 32;
    for (int j = tid; j < 32 * 16; j += 256) {
        int rl = j >> 4, q = j & 15;
        if (node0 + rl >= N_NODES) continue;
        int c = cnt2[rl] < 128 ? cnt2[rl] : 128;
        float dv = rsqrtf((float)c + 1.0f);
        uint4 g = Gh4[(size_t)(node0 + rl) * 16 + q];
        g.x = pack_f16x2(f16lo(g.x) * dv, f16hi(g.x) * dv);
        g.y = pack_f16x2(f16lo(g.y) * dv, f16hi(g.y) * dv);
        g.z = pack_f16x2(f16lo(g.z) * dv, f16hi(g.z) * dv);
        g.w = pack_f16x2(f16lo(g.w) * dv, f16hi(g.w) * dv);
        Gh4[(size_t)(node0 + rl) * 16 + q] = g;
    }
}

// ---------------- fused agg via packed-f16 dot2 -> LDS (input always prescaled) ----
template <bool PACK_OUT>
__device__ __forceinline__ void agg_to_lds(const ushort16* __restrict__ Gh,
                                           const int* __restrict__ deg,
                                           const ushort16* __restrict__ col,
                                           const float* __restrict__ dis,
                                           void* __restrict__ Xout) {
    int tid  = threadIdx.x;
    int wave = tid >> 6;
    int lane = tid & 63;
    int grp  = lane >> 4;       // 0..3 : which edge of the 4-per-load
    int sl   = lane & 15;       // 0..15: 16B slice of the 256B row
    const uint32* g32 = (const uint32*)Gh;
    const uint32* gp  = g32 + (sl << 2);   // +sl*16B within a row

#pragma unroll
    for (int i = 0; i < 2; i++) {
        int vr = wave * 2 + i;              // local node 0..7
        int v  = blockIdx.x * NPB + vr;
        int dv = deg[v];
        uint32 colpack = ((const uint32*)(col + ((size_t)v << 7)))[lane];
        float acc[8];
#pragma unroll
        for (int j = 0; j < 8; j++) acc[j] = 0.f;

        int kk = 0;
        for (; kk + 16 <= dv; kk += 16) {
            int k0 = kk + grp, k1 = kk + 4 + grp, k2 = kk + 8 + grp, k3 = kk + 12 + grp;
            uint32 cp0 = __shfl(colpack, k0 >> 1, 64);
            uint32 cp1 = __shfl(colpack, k1 >> 1, 64);
            uint32 cp2 = __shfl(colpack, k2 >> 1, 64);
            uint32 cp3 = __shfl(colpack, k3 >> 1, 64);
            int u0 = (k0 & 1) ? (int)(cp0 >> 16) : (int)(cp0 & 0xffffu);
            int u1 = (k1 & 1) ? (int)(cp1 >> 16) : (int)(cp1 & 0xffffu);
            int u2 = (k2 & 1) ? (int)(cp2 >> 16) : (int)(cp2 & 0xffffu);
            int u3 = (k3 & 1) ? (int)(cp3 >> 16) : (int)(cp3 & 0xffffu);
            uint4 w0 = *(const uint4*)(gp + (u0 << 6));
            uint4 w1 = *(const uint4*)(gp + (u1 << 6));
            uint4 w2 = *(const uint4*)(gp + (u2 << 6));
            uint4 w3 = *(const uint4*)(gp + (u3 << 6));
            acc[0] = fd2(w0.x, SEL_LO, acc[0]); acc[1] = fd2(w0.x, SEL_HI, acc[1]);
            acc[2] = fd2(w0.y, SEL_LO, acc[2]); acc[3] = fd2(w0.y, SEL_HI, acc[3]);
            acc[4] = fd2(w0.z, SEL_LO, acc[4]); acc[5] = fd2(w0.z, SEL_HI, acc[5]);
            acc[6] = fd2(w0.w, SEL_LO, acc[6]); acc[7] = fd2(w0.w, SEL_HI, acc[7]);
            acc[0] = fd2(w1.x, SEL_LO, acc[0]); acc[1] = fd2(w1.x, SEL_HI, acc[1]);
            acc[2] = fd2(w1.y, SEL_LO, acc[2]); acc[3] = fd2(w1.y, SEL_HI, acc[3]);
            acc[4] = fd2(w1.z, SEL_LO, acc[4]); acc[5] = fd2(w1.z, SEL_HI, acc[5]);
            acc[6] = fd2(w1.w, SEL_LO, acc[6]); acc[7] = fd2(w1.w, SEL_HI, acc[7]);
            acc[0] = fd2(w2.x, SEL_LO, acc[0]); acc[1] = fd2(w2.x, SEL_HI, acc[1]);
            acc[2] = fd2(w2.y, SEL_LO, acc[2]); acc[3] = fd2(w2.y, SEL_HI, acc[3]);
            acc[4] = fd2(w2.z, SEL_LO, acc[4]); acc[5] = fd2(w2.z, SEL_HI, acc[5]);
            acc[6] = fd2(w2.w, SEL_LO, acc[6]); acc[7] = fd2(w2.w, SEL_HI, acc[7]);
            acc[0] = fd2(w3.x, SEL_LO, acc[0]); acc[1] = fd2(w3.x, SEL_HI, acc[1]);
            acc[2] = fd2(w3.y, SEL_LO, acc[2]); acc[3] = fd2(w3.y, SEL_HI, acc[3]);
            acc[4] = fd2(w3.z, SEL_LO, acc[4]); acc[5] = fd2(w3.z, SEL_HI, acc[5]);
            acc[6] = fd2(w3.w, SEL_LO, acc[6]); acc[7] = fd2(w3.w, SEL_HI, acc[7]);
        }
        for (; kk + 8 <= dv; kk += 8) {
            int k0 = kk + grp, k1 = kk + 4 + grp;
            uint32 cp0 = __shfl(colpack, k0 >> 1, 64);
            uint32 cp1 = __shfl(colpack, k1 >> 1, 64);
            int u0 = (k0 & 1) ? (int)(cp0 >> 16) : (int)(cp0 & 0xffffu);
            int u1 = (k1 & 1) ? (int)(cp1 >> 16) : (int)(cp1 & 0xffffu);
            uint4 w0 = *(const uint4*)(gp + (u0 << 6));
            uint4 w1 = *(const uint4*)(gp + (u1 << 6));
            acc[0] = fd2(w0.x, SEL_LO, acc[0]); acc[1] = fd2(w0.x, SEL_HI, acc[1]);
            acc[2] = fd2(w0.y, SEL_LO, acc[2]); acc[3] = fd2(w0.y, SEL_HI, acc[3]);
            acc[4] = fd2(w0.z, SEL_LO, acc[4]); acc[5] = fd2(w0.z, SEL_HI, acc[5]);
            acc[6] = fd2(w0.w, SEL_LO, acc[6]); acc[7] = fd2(w0.w, SEL_HI, acc[7]);
            acc[0] = fd2(w1.x, SEL_LO, acc[0]); acc[1] = fd2(w1.x, SEL_HI, acc[1]);
            acc[2] = fd2(w1.y, SEL_LO, acc[2]); acc[3] = fd2(w1.y, SEL_HI, acc[3]);
            acc[4] = fd2(w1.z, SEL_LO, acc[4]); acc[5] = fd2(w1.z, SEL_HI, acc[5]);
            acc[6] = fd2(w1.w, SEL_LO, acc[6]); acc[7] = fd2(w1.w, SEL_HI, acc[7]);
        }
        for (; kk < dv; kk += 4) {
            int k = kk + grp;
            uint32 cp = __shfl(colpack, (k >> 1) & 63, 64);
            int u = (k & 1) ? (int)(cp >> 16) : (int)(cp & 0xffffu);
            if (k < dv) {
                uint4 w = *(const uint4*)(gp + (u << 6));
                acc[0] = fd2(w.x, SEL_LO, acc[0]); acc[1] = fd2(w.x, SEL_HI, acc[1]);
                acc[2] = fd2(w.y, SEL_LO, acc[2]); acc[3] = fd2(w.y, SEL_HI, acc[3]);
                acc[4] = fd2(w.z, SEL_LO, acc[4]); acc[5] = fd2(w.z, SEL_HI, acc[5]);
                acc[6] = fd2(w.w, SEL_LO, acc[6]); acc[7] = fd2(w.w, SEL_HI, acc[7]);
            }
        }
#pragma unroll
        for (int j = 0; j < 8; j++) {
            acc[j] += __shfl_xor(acc[j], 16, 64);
            acc[j] += __shfl_xor(acc[j], 32, 64);
        }
        float sv = dis[v];
        uint4 hs = *(const uint4*)(gp + (v << 6));
        float r0 = sv * (acc[0] + f16lo(hs.x));
        float r1 = sv * (acc[1] + f16hi(hs.x));
        float r2 = sv * (acc[2] + f16lo(hs.y));
        float r3 = sv * (acc[3] + f16hi(hs.y));
        float r4 = sv * (acc[4] + f16lo(hs.z));
        float r5 = sv * (acc[5] + f16hi(hs.z));
        float r6 = sv * (acc[6] + f16lo(hs.w));
        float r7 = sv * (acc[7] + f16hi(hs.w));
        if (grp == 0) {
            if (PACK_OUT) {
                uint32* o = (uint32*)Xout + vr * 64 + sl * 4;
                uint4 pk4;
                pk4.x = pack_f16x2(fmaxf(r0, 0.f), fmaxf(r1, 0.f));
                pk4.y = pack_f16x2(fmaxf(r2, 0.f), fmaxf(r3, 0.f));
                pk4.z = pack_f16x2(fmaxf(r4, 0.f), fmaxf(r5, 0.f));
                pk4.w = pack_f16x2(fmaxf(r6, 0.f), fmaxf(r7, 0.f));
                *(uint4*)o = pk4;
            } else {
                float4* o = (float4*)((float*)Xout + vr * DIM + sl * 8);
                o[0] = make_float4(fmaxf(r0, 0.f), fmaxf(r1, 0.f),
                                   fmaxf(r2, 0.f), fmaxf(r3, 0.f));
                o[1] = make_float4(fmaxf(r4, 0.f), fmaxf(r5, 0.f),
                                   fmaxf(r6, 0.f), fmaxf(r7, 0.f));
            }
        }
    }
}

// ---------------- fused layer: dot2-agg (packed LDS) + dot2-GEMM ----------------
__global__ __launch_bounds__(256) void fused_layer(const ushort16* __restrict__ Gh_in,
                                                   const int* __restrict__ deg,
                                                   const ushort16* __restrict__ col,
                                                   const float* __restrict__ dis,
                                                   const uint32* __restrict__ Wp,
                                                   ushort16* __restrict__ Gh_out) {
    __shared__ __align__(16) uint32 Xh[NPB * 64];   // 2 KB packed f16 pairs
    agg_to_lds<true>(Gh_in, deg, col, dis, Xh);
    __syncthreads();

    int c  = threadIdx.x & 127;
    int rg = threadIdx.x >> 7;
    int row0 = blockIdx.x * NPB + rg * 4;
    const uint4* Xh4 = (const uint4*)Xh;
    float acc[4] = {0.f, 0.f, 0.f, 0.f};
    for (int q = 0; q < 16; q++) {
        uint32 wp0 = Wp[(4 * q + 0) * DIM + c];
        uint32 wp1 = Wp[(4 * q + 1) * DIM + c];
        uint32 wp2 = Wp[(4 * q + 2) * DIM + c];
        uint32 wp3 = Wp[(4 * q + 3) * DIM + c];
#pragma unroll
        for (int r = 0; r < 4; r++) {
            uint4 xv = Xh4[(rg * 4 + r) * 16 + q];
            acc[r] = fd2(xv.x, wp0, acc[r]);
            acc[r] = fd2(xv.y, wp1, acc[r]);
            acc[r] = fd2(xv.z, wp2, acc[r]);
            acc[r] = fd2(xv.w, wp3, acc[r]);
        }
    }
#pragma unroll
    for (int r = 0; r < 4; r++) {
        int row = row0 + r;
        Gh_out[row * DIM + c] = f32_f16(acc[r] * dis[row]);
    }
}

// ---------------- fused last: dot2-agg (f32 LDS) + head + pool ----------------
__global__ __launch_bounds__(256) void fused_last(const ushort16* __restrict__ Gh_in,
                                                  const int* __restrict__ deg,
                                                  const ushort16* __restrict__ col,
                                                  const float* __restrict__ dis,
                                                  const int* __restrict__ batch,
                                                  const float* __restrict__ fcw,
                                                  const float* __restrict__ fcb,
                                                  float* __restrict__ xr,
                                                  float* __restrict__ out) {
    __shared__ float Xs[NPB * DIM];
    agg_to_lds<false>(Gh_in, deg, col, dis, Xs);
    __syncthreads();

    int wave = threadIdx.x >> 6;
    int lane = threadIdx.x & 63;
#pragma unroll
    for (int i = 0; i < 2; i++) {
        int vr   = wave * 2 + i;
        int node = blockIdx.x * NPB + vr;
        float xl = Xs[vr * DIM + lane];
        float xh = Xs[vr * DIM + 64 + lane];
        float lg[NCLS];
#pragma unroll
        for (int c2 = 0; c2 < NCLS; c2++) {
            float p = xl * fcw[lane * NCLS + c2] + xh * fcw[(lane + 64) * NCLS + c2];
#pragma unroll
            for (int off = 32; off >= 1; off >>= 1) p += __shfl_xor(p, off, 64);
            lg[c2] = p + fcb[c2];
        }
        float m = lg[0];
#pragma unroll
        for (int c2 = 1; c2 < NCLS; c2++) m = fmaxf(m, lg[c2]);
        float s = 0.f;
#pragma unroll
        for (int c2 = 0; c2 < NCLS; c2++) s += expf(lg[c2] - m);
        float lse = m + logf(s);
        if (lane < NCLS) out[node * NCLS + lane] = lg[lane] - lse;
    }

    // pool: batch is sorted, run-length flush (<= ~1 extra flush per block)
    if (threadIdx.x < 128) {
        int start = blockIdx.x * NPB;
        int t = threadIdx.x;
        int b = batch[start];
        float a = 0.f;
        for (int n = 0; n < NPB; n++) {
            int bn = batch[start + n];
            if (bn != b) { atomicAdd(&xr[b * DIM + t], a); a = 0.f; b = bn; }
            a += Xs[n * DIM + t];
        }
        atomicAdd(&xr[b * DIM + t], a);
    }
}

// ---------------- launch ----------------

extern "C" void kernel_launch(void* const* d_in, const int* in_sizes, int n_in,
                              void* d_out, int out_size, void* d_ws, size_t ws_size,
                              hipStream_t stream) {
    const float* x     = (const float*)d_in[0];
    const int*   ei    = (const int*)d_in[1];      // [2, E] int32
    const int*   src   = ei;
    const int*   dst   = ei + N_EDGES;
    const int*   batch = (const int*)d_in[2];
    const float* W1    = (const float*)d_in[3];
    const float* W2    = (const float*)d_in[4];
    const float* W3    = (const float*)d_in[5];
    const float* W4    = (const float*)d_in[6];
    const float* fcw   = (const float*)d_in[7];
    const float* fcb   = (const float*)d_in[8];

    float* out_ls = (float*)d_out;                 // [N,10]
    float* out_xr = out_ls + N_NODES * NCLS;       // [64,128]

    // workspace layout (16B-aligned element offsets)
    int*      gcursor = (int*)d_ws;                       // 256 ints
    int*      deg     = gcursor + 256;                    // 10240 ints
    float*    dis     = (float*)(deg + 10240);            // 10240 floats
    uint32*   bins    = (uint32*)(dis + 10240);           // NB*BCAP uint32 (2.89MB)
    ushort16* col     = (ushort16*)(bins + NB * BCAP);    // NB*64*128 ushorts (2.57MB)
    ushort16* Gh_a    = col + (size_t)NB * 64 * 128;      // N*D f16
    ushort16* Gh_b    = Gh_a + (size_t)N_NODES * DIM;     // N*D f16
    uint32*   Wp      = (uint32*)(Gh_b + (size_t)N_NODES * DIM); // 3*64*128 f16-pairs

    hipMemsetAsync(gcursor, 0, 256 * sizeof(int), stream);

    binA_gemm1<<<789, 256, 0, stream>>>(src, dst, gcursor, bins, x, W1,
                                        W2, W3, W4, Wp, Gh_a, out_xr);
    binB2     <<<2 * NB, 256, 0, stream>>>(gcursor, bins, col, deg, dis, Gh_a);

    fused_layer<<<N_NODES / NPB, 256, 0, stream>>>(Gh_a, deg, col, dis, Wp, Gh_b);
    fused_layer<<<N_NODES / NPB, 256, 0, stream>>>(Gh_b, deg, col, dis,
                                                   Wp + 64 * DIM, Gh_a);
    fused_layer<<<N_NODES / NPB, 256, 0, stream>>>(Gh_a, deg, col, dis,
                                                   Wp + 2 * 64 * DIM, Gh_b);
    fused_last <<<N_NODES / NPB, 256, 0, stream>>>(Gh_b, deg, col, dis, batch,
                                                   fcw, fcb, out_xr, out_ls);
}